// Round 2
// baseline (2868.340 us; speedup 1.0000x reference)
//
#include <hip/hip_runtime.h>

#define TSTEPS 2048
#define HID 32

// sigmoid via v_exp + v_rcp (fast intrinsics; threshold is ~9.6e-3, plenty)
__device__ __forceinline__ float fast_sigmoid(float x) {
    float e = __expf(-x);
    return __fdividef(1.0f, 1.0f + e);
}
__device__ __forceinline__ float fast_tanh(float x) {
    // tanh(x) = 1 - 2/(exp(2x)+1); saturates correctly at +/-1
    float e = __expf(2.0f * x);
    return 1.0f - __fdividef(2.0f, e + 1.0f);
}

// One wave = 2 batch elements (one per 32-lane half). Lane j (0..31 within its
// half) owns hidden unit j: keeps c_j in a register, computes gates i,f,g,o of
// unit j (W_hh rows j, 32+j, 64+j, 96+j cached in 128 VGPRs). h is broadcast
// through a per-half-wave LDS slot; wave-lockstep + in-order LDS pipe + explicit
// lgkmcnt(0) fence gives correctness without __syncthreads.
extern "C" __global__ void __launch_bounds__(256)
lstm_fused(const float* __restrict__ x,     // [B, T]
           const float* __restrict__ W_ih,  // [128]
           const float* __restrict__ W_hh,  // [128, 32]
           const float* __restrict__ b_ih,  // [128]
           const float* __restrict__ b_hh,  // [128]
           const float* __restrict__ W3,    // [32, 32]
           const float* __restrict__ b3,    // [32]
           const float* __restrict__ W4,    // [32]
           const float* __restrict__ b4,    // [1]
           float* __restrict__ out)         // [B]
{
    const int tid  = threadIdx.x;
    const int lane = tid & 63;
    const int half = lane >> 5;
    const int j    = lane & 31;
    const int slot = ((tid >> 6) << 1) + half;      // 0..7 per block
    const int batch = blockIdx.x * 8 + slot;

    __shared__ float h_lds[8][HID];

    // cache W_hh rows for this lane's 4 gates (gate g row = g*32 + j)
    float w[4][HID];
    #pragma unroll
    for (int g = 0; g < 4; ++g) {
        const float4* row = reinterpret_cast<const float4*>(W_hh + (size_t)(g * HID + j) * HID);
        #pragma unroll
        for (int q = 0; q < 8; ++q) {
            float4 v = row[q];
            w[g][4*q+0] = v.x; w[g][4*q+1] = v.y; w[g][4*q+2] = v.z; w[g][4*q+3] = v.w;
        }
    }
    float wih[4], bias[4];
    #pragma unroll
    for (int g = 0; g < 4; ++g) {
        wih[g]  = W_ih[g * HID + j];
        bias[g] = b_ih[g * HID + j] + b_hh[g * HID + j];
    }

    float c = 0.0f;
    h_lds[slot][j] = 0.0f;
    asm volatile("s_waitcnt lgkmcnt(0)" ::: "memory");

    const float* xb = x + (size_t)batch * TSTEPS;

    for (int t0 = 0; t0 < TSTEPS; t0 += 4) {
        const float4 xv = *reinterpret_cast<const float4*>(xb + t0);
        float xs[4] = {xv.x, xv.y, xv.z, xv.w};
        #pragma unroll
        for (int tt = 0; tt < 4; ++tt) {
            // broadcast-read all 32 h values of this half's batch
            float hk[HID];
            #pragma unroll
            for (int q = 0; q < 8; ++q) {
                float4 hv = *reinterpret_cast<const float4*>(&h_lds[slot][4*q]);
                hk[4*q+0]=hv.x; hk[4*q+1]=hv.y; hk[4*q+2]=hv.z; hk[4*q+3]=hv.w;
            }
            float a0 = fmaf(xs[tt], wih[0], bias[0]);
            float a1 = fmaf(xs[tt], wih[1], bias[1]);
            float a2 = fmaf(xs[tt], wih[2], bias[2]);
            float a3 = fmaf(xs[tt], wih[3], bias[3]);
            #pragma unroll
            for (int k = 0; k < HID; ++k) {
                a0 = fmaf(hk[k], w[0][k], a0);
                a1 = fmaf(hk[k], w[1][k], a1);
                a2 = fmaf(hk[k], w[2][k], a2);
                a3 = fmaf(hk[k], w[3][k], a3);
            }
            float ig = fast_sigmoid(a0);
            float fg = fast_sigmoid(a1);
            float gg = fast_tanh(a2);
            float og = fast_sigmoid(a3);
            c = fmaf(fg, c, ig * gg);
            float hn = og * fast_tanh(c);
            h_lds[slot][j] = hn;
            // ensure write retired before next step's cross-lane reads;
            // "memory" clobber stops the compiler reordering LDS ops across it
            asm volatile("s_waitcnt lgkmcnt(0)" ::: "memory");
        }
    }

    // ---- head: out = relu(h @ W3^T + b3); clf = sigmoid(out @ W4^T + b4) ----
    float hk[HID];
    #pragma unroll
    for (int q = 0; q < 8; ++q) {
        float4 hv = *reinterpret_cast<const float4*>(&h_lds[slot][4*q]);
        hk[4*q+0]=hv.x; hk[4*q+1]=hv.y; hk[4*q+2]=hv.z; hk[4*q+3]=hv.w;
    }
    float acc = b3[j];
    const float4* w3row = reinterpret_cast<const float4*>(W3 + (size_t)j * HID);
    #pragma unroll
    for (int q = 0; q < 8; ++q) {
        float4 wv = w3row[q];
        acc = fmaf(hk[4*q+0], wv.x, acc);
        acc = fmaf(hk[4*q+1], wv.y, acc);
        acc = fmaf(hk[4*q+2], wv.z, acc);
        acc = fmaf(hk[4*q+3], wv.w, acc);
    }
    acc = fmaxf(acc, 0.0f);

    float v = acc * W4[j];
    #pragma unroll
    for (int off = 16; off >= 1; off >>= 1)
        v += __shfl_xor(v, off, 32);
    if (j == 0)
        out[batch] = fast_sigmoid(v + b4[0]);
}

extern "C" void kernel_launch(void* const* d_in, const int* in_sizes, int n_in,
                              void* d_out, int out_size, void* d_ws, size_t ws_size,
                              hipStream_t stream) {
    const float* x    = (const float*)d_in[0];
    const float* W_ih = (const float*)d_in[1];
    const float* W_hh = (const float*)d_in[2];
    const float* b_ih = (const float*)d_in[3];
    const float* b_hh = (const float*)d_in[4];
    const float* W3   = (const float*)d_in[5];
    const float* b3   = (const float*)d_in[6];
    const float* W4   = (const float*)d_in[7];
    const float* b4   = (const float*)d_in[8];
    float* out = (float*)d_out;

    const int batches = out_size;            // 8192
    const int blocks  = batches / 8;         // 8 batches per 256-thread block
    lstm_fused<<<blocks, 256, 0, stream>>>(x, W_ih, W_hh, b_ih, b_hh, W3, b3, W4, b4, out);
}

// Round 3
// 1625.692 us; speedup vs baseline: 1.7644x; 1.7644x over previous
//
#include <hip/hip_runtime.h>
#include <stdint.h>

#define TSTEPS 2048
#define L2E 1.4426950408889634f   // log2(e)

typedef _Float16 half8 __attribute__((ext_vector_type(8)));
typedef float    f32x4 __attribute__((ext_vector_type(4)));

// One wave (64 threads) = 16 batch sequences.
// Gates [16 x 128] = h[16 x 32] @ W_hh^T via 8x mfma_f32_16x16x32_f16.
// Weights pre-scaled by -log2e (i,f,o) / +2log2e (g) so v_exp_f32 (2^x)
// consumes the accumulator directly:
//   sigmoid(a) = rcp(1 + 2^(-a*log2e)),  tanh(a) = 1 - 2*rcp(1 + 2^(2a*log2e))
// D-tile mapping (m89-verified): value (lane, reg r) = D[batch=(lane>>4)*4+r,
// gate = 16n + (lane&15)] -> each lane owns gates i,f,g,o of units
// {cidx, cidx+16} for 4 batches; c-state stays in 8 VGPRs, no cross-lane.
// h feedback via f16 LDS [16][36] (72B row stride -> <=2-way bank aliasing,
// and A-frag k 0..7 blocks stay 16B-contiguous, 8B-aligned for ds_read_b64).
extern "C" __global__ void __launch_bounds__(64)
lstm_mfma(const float* __restrict__ x,     // [B, T]
          const float* __restrict__ W_ih,  // [128]
          const float* __restrict__ W_hh,  // [128, 32]
          const float* __restrict__ b_ih,  // [128]
          const float* __restrict__ b_hh,  // [128]
          const float* __restrict__ W3,    // [32, 32]
          const float* __restrict__ b3,    // [32]
          const float* __restrict__ W4,    // [32]
          const float* __restrict__ b4,    // [1]
          float* __restrict__ out)         // [B]
{
    const int lane  = threadIdx.x;
    const int cidx  = lane & 15;
    const int quad  = lane >> 4;
    const int batch0 = blockIdx.x * 16;

    __shared__ _Float16 hsh[16 * 36];   // 72-byte row stride, 1152 B

    // ---- static per-lane data ------------------------------------------
    // B-frag tile n: lane holds B[k = quad*8+q][gatecol = 16n+cidx]
    half8 bfrag[8];
    float wihs[8], biass[8];
    #pragma unroll
    for (int n = 0; n < 8; ++n) {
        const int g = 16 * n + cidx;                    // gate row 0..127
        const float s = (n == 4 || n == 5) ? (2.0f * L2E) : (-L2E);
        const float* wr = W_hh + g * 32 + quad * 8;     // 32B aligned
        float4 w0 = *(const float4*)(wr);
        float4 w1 = *(const float4*)(wr + 4);
        half8 hb;
        hb[0] = (_Float16)(w0.x * s); hb[1] = (_Float16)(w0.y * s);
        hb[2] = (_Float16)(w0.z * s); hb[3] = (_Float16)(w0.w * s);
        hb[4] = (_Float16)(w1.x * s); hb[5] = (_Float16)(w1.y * s);
        hb[6] = (_Float16)(w1.z * s); hb[7] = (_Float16)(w1.w * s);
        bfrag[n] = hb;
        wihs[n]  = W_ih[g] * s;
        biass[n] = (b_ih[g] + b_hh[g]) * s;
    }

    // c state: (h2 = unit-half, r = batch-reg)
    float cst[2][4];
    #pragma unroll
    for (int h2 = 0; h2 < 2; ++h2)
        #pragma unroll
        for (int r = 0; r < 4; ++r) cst[h2][r] = 0.0f;

    // zero h in LDS (every (batch,unit) cell covered exactly once)
    #pragma unroll
    for (int h2 = 0; h2 < 2; ++h2)
        #pragma unroll
        for (int r = 0; r < 4; ++r)
            hsh[(quad * 4 + r) * 36 + h2 * 16 + cidx] = (_Float16)0.0f;
    asm volatile("s_waitcnt lgkmcnt(0)" ::: "memory");

    // x pointers: lane needs x[batch = batch0 + quad*4 + r][t]
    const float* xp0 = x + (size_t)(batch0 + quad * 4 + 0) * TSTEPS;
    const float* xp1 = x + (size_t)(batch0 + quad * 4 + 1) * TSTEPS;
    const float* xp2 = x + (size_t)(batch0 + quad * 4 + 2) * TSTEPS;
    const float* xp3 = x + (size_t)(batch0 + quad * 4 + 3) * TSTEPS;

    float4 xn0 = *(const float4*)(xp0);
    float4 xn1 = *(const float4*)(xp1);
    float4 xn2 = *(const float4*)(xp2);
    float4 xn3 = *(const float4*)(xp3);

    const int abyte = cidx * 72 + quad * 16;   // A-frag base byte in LDS
    const char* hbytes = (const char*)hsh;

    for (int t0 = 0; t0 < TSTEPS; t0 += 4) {
        float4 xc0 = xn0, xc1 = xn1, xc2 = xn2, xc3 = xn3;
        if (t0 + 4 < TSTEPS) {                 // prefetch next 4 steps
            xn0 = *(const float4*)(xp0 + t0 + 4);
            xn1 = *(const float4*)(xp1 + t0 + 4);
            xn2 = *(const float4*)(xp2 + t0 + 4);
            xn3 = *(const float4*)(xp3 + t0 + 4);
        }
        #pragma unroll
        for (int tt = 0; tt < 4; ++tt) {
            // ---- A fragment: h[m=cidx][k=quad*8+q] ----
            union { uint2 u2[2]; half8 h; } af;
            af.u2[0] = *(const uint2*)(hbytes + abyte);
            af.u2[1] = *(const uint2*)(hbytes + abyte + 8);

            const float xs0 = ((const float*)&xc0)[tt];
            const float xs1 = ((const float*)&xc1)[tt];
            const float xs2 = ((const float*)&xc2)[tt];
            const float xs3 = ((const float*)&xc3)[tt];

            // ---- acc init: scaled (x*W_ih + bias) ----
            f32x4 acc[8];
            #pragma unroll
            for (int n = 0; n < 8; ++n) {
                acc[n][0] = fmaf(xs0, wihs[n], biass[n]);
                acc[n][1] = fmaf(xs1, wihs[n], biass[n]);
                acc[n][2] = fmaf(xs2, wihs[n], biass[n]);
                acc[n][3] = fmaf(xs3, wihs[n], biass[n]);
            }
            // ---- gates = h @ Ws^T ----
            #pragma unroll
            for (int n = 0; n < 8; ++n)
                acc[n] = __builtin_amdgcn_mfma_f32_16x16x32_f16(
                             af.h, bfrag[n], acc[n], 0, 0, 0);

            // ---- activations + state update (all lane-local) ----
            #pragma unroll
            for (int h2 = 0; h2 < 2; ++h2) {
                #pragma unroll
                for (int r = 0; r < 4; ++r) {
                    float ei = __builtin_amdgcn_exp2f(acc[0 + h2][r]);
                    float ef = __builtin_amdgcn_exp2f(acc[2 + h2][r]);
                    float eg = __builtin_amdgcn_exp2f(acc[4 + h2][r]);
                    float eo = __builtin_amdgcn_exp2f(acc[6 + h2][r]);
                    float si = __builtin_amdgcn_rcpf(1.0f + ei);
                    float sf = __builtin_amdgcn_rcpf(1.0f + ef);
                    float tg = fmaf(-2.0f, __builtin_amdgcn_rcpf(1.0f + eg), 1.0f);
                    float so = __builtin_amdgcn_rcpf(1.0f + eo);
                    float cn = fmaf(sf, cst[h2][r], si * tg);
                    cst[h2][r] = cn;
                    float ec = __builtin_amdgcn_exp2f(cn * (2.0f * L2E));
                    float tc = fmaf(-2.0f, __builtin_amdgcn_rcpf(1.0f + ec), 1.0f);
                    float hv = so * tc;
                    hsh[(quad * 4 + r) * 36 + h2 * 16 + cidx] = (_Float16)hv;
                }
            }
            // writes must retire before next step's A-frag reads (same-wave
            // LDS is in-order; clobber stops compiler reordering)
            asm volatile("s_waitcnt lgkmcnt(0)" ::: "memory");
        }
    }

    // ---- head: per-batch, computed redundantly by 4 quads, quad 0 writes --
    float hk[32];
    #pragma unroll
    for (int k = 0; k < 32; ++k) hk[k] = (float)hsh[cidx * 36 + k];

    float v = 0.0f;
    #pragma unroll
    for (int j = 0; j < 32; ++j) {
        const float4* w3r = (const float4*)(W3 + j * 32);
        float a = b3[j];
        #pragma unroll
        for (int q = 0; q < 8; ++q) {
            float4 wv = w3r[q];
            a = fmaf(hk[4 * q + 0], wv.x, a);
            a = fmaf(hk[4 * q + 1], wv.y, a);
            a = fmaf(hk[4 * q + 2], wv.z, a);
            a = fmaf(hk[4 * q + 3], wv.w, a);
        }
        a = fmaxf(a, 0.0f);
        v = fmaf(a, W4[j], v);
    }
    if (quad == 0) {
        float e = __builtin_amdgcn_exp2f(-(v + b4[0]) * L2E);
        out[batch0 + cidx] = __builtin_amdgcn_rcpf(1.0f + e);
    }
}

extern "C" void kernel_launch(void* const* d_in, const int* in_sizes, int n_in,
                              void* d_out, int out_size, void* d_ws, size_t ws_size,
                              hipStream_t stream) {
    const float* x    = (const float*)d_in[0];
    const float* W_ih = (const float*)d_in[1];
    const float* W_hh = (const float*)d_in[2];
    const float* b_ih = (const float*)d_in[3];
    const float* b_hh = (const float*)d_in[4];
    const float* W3   = (const float*)d_in[5];
    const float* b3   = (const float*)d_in[6];
    const float* W4   = (const float*)d_in[7];
    const float* b4   = (const float*)d_in[8];
    float* out = (float*)d_out;

    const int batches = out_size;          // 8192
    const int blocks  = batches / 16;      // 512 waves, one per 64-thread WG
    lstm_mfma<<<blocks, 64, 0, stream>>>(x, W_ih, W_hh, b_ih, b_hh,
                                         W3, b3, W4, b4, out);
}